// Round 11
// baseline (273.353 us; speedup 1.0000x reference)
//
#include <hip/hip_runtime.h>

// modConv: y = demod(b,fo) * conv3x3(x * s(b,fi), w * w_scale)
// bf16 MFMA implicit GEMM (M=fo, N=pixels, K=fi, 9 taps accumulated).
// R16: launch-graph restructure; conv core reverted to R11 (measured best,
//     125.4us). (a) ONE prep kernel: {wsq_wt | style | zero | modx x4rows};
//     modx blocks compute their own s inline (32x512-dot, fc_w L2-resident)
//     to break the style->modx dependency. (b) demod folded into k_conv
//     prologue (s row->LDS, 64 float4 MACs/thread, pair shfl, rsqrt->LDS),
//     overlapped with x/w staging via raw barrier (no vmcnt drain).
//     2 launches total (was 3); 4097 prep blocks (was 11265).

typedef __bf16 bf16_t;
typedef __bf16 bf16x8 __attribute__((ext_vector_type(8)));
typedef float floatx4 __attribute__((ext_vector_type(4)));

#define HW_ 4096
#define FCSCALE 0.04419417382415922f   /* 512^-0.5 */
#define WSCALE  0.014731391274719742f  /* (512*9)^-0.5 */

#define VMCNT(n) asm volatile("s_waitcnt vmcnt(" #n ")" ::: "memory")

__device__ __forceinline__ void gload_lds16(const bf16_t* g, bf16_t* l) {
  __builtin_amdgcn_global_load_lds(
      (const __attribute__((address_space(1))) void*)g,
      (__attribute__((address_space(3))) void*)l, 16, 0, 0);
}

// ---- prep bodies ----

__device__ __forceinline__ void style_body(int bid, int t,
    const float* __restrict__ style, const float* __restrict__ fc_w,
    const float* __restrict__ fc_b, float* __restrict__ s_out) {
  int o = bid * 4 + (t >> 6);                   // 0..4095 = b*512+fi
  int lane = t & 63;
  int b = o >> 9, fi = o & 511;
  const float4* st = (const float4*)(style + b * 512);
  const float4* fw = (const float4*)(fc_w + (size_t)fi * 512);
  float4 a0 = st[lane * 2],     w0 = fw[lane * 2];
  float4 a1 = st[lane * 2 + 1], w1 = fw[lane * 2 + 1];
  float acc = a0.x * w0.x + a0.y * w0.y + a0.z * w0.z + a0.w * w0.w
            + a1.x * w1.x + a1.y * w1.y + a1.z * w1.z + a1.w * w1.w;
#pragma unroll
  for (int d = 32; d >= 1; d >>= 1) acc += __shfl_xor(acc, d, 64);
  if (lane == 0) s_out[o] = acc * FCSCALE + fc_b[fi];
}

__device__ __forceinline__ void wsq_wt_body(int bid, int t,
    const float* __restrict__ w, float* __restrict__ wsq, bf16_t* __restrict__ wt) {
  int idx = bid * 256 + t;                      // fo*512+fi
  int fo = idx >> 9, fi = idx & 511;
  const float* wp = w + (size_t)idx * 9;
  float v[9], q = 0.f;
#pragma unroll
  for (int k = 0; k < 9; ++k) { v[k] = wp[k] * WSCALE; q += v[k] * v[k]; }
  wsq[idx] = q;
#pragma unroll
  for (int k = 0; k < 9; ++k)
    wt[((((size_t)k * 64) + (fi >> 3)) * 512 + fo) * 8 + (fi & 7)] = (bf16_t)v[k];
}

// xT[b][h][g][w][8] = bf16(x[b][g*8+j][h][w] * s)  (granule-major rows);
// sv comes from block-local s_loc[32]
__device__ __forceinline__ void modx_body_loc(int fi0, int h, int b, int t,
    const float* __restrict__ x, const float* __restrict__ s_loc,
    bf16_t* __restrict__ xT, float (*tile)[65]) {
  int c4 = (t & 15) * 4, fr = t >> 4;            // float4 coalesced reads
#pragma unroll
  for (int i = 0; i < 2; ++i) {
    int fi_l = i * 16 + fr;
    float sv = s_loc[fi_l];
    float4 v = *(const float4*)(x + ((size_t)(b * 512 + fi0 + fi_l)) * HW_ + h * 64 + c4);
    tile[fi_l][c4] = v.x * sv; tile[fi_l][c4 + 1] = v.y * sv;
    tile[fi_l][c4 + 2] = v.z * sv; tile[fi_l][c4 + 3] = v.w * sv;
  }
  __syncthreads();
  int g_l = t >> 6, wcol = t & 63;               // write granule (g_l) x col
  bf16x8 vv;
#pragma unroll
  for (int j = 0; j < 8; ++j) vv[j] = (bf16_t)tile[g_l * 8 + j][wcol];
  *(bf16x8*)&xT[((((size_t)(b * 64 + h)) * 64 + (fi0 >> 3) + g_l) * 64 + wcol) * 8] = vv;
}

// ONE prep kernel. blocks: [0,1024) wsq_wt; [1024,2048) style; 2048 zerobuf;
// [2049,4097) modx4: m=blk-2049: b=m>>8, hq=(m&255)>>4, fi0=(m&15)*32.
// modx4 computes its own s[fi0..fi0+32) (breaks dependency on style blocks),
// then 4 rows h=hq*4..hq*4+3 of the modulate+transpose.
__global__ void k_prep(const float* __restrict__ style, const float* __restrict__ fc_w,
                       const float* __restrict__ fc_b, const float* __restrict__ w,
                       const float* __restrict__ x,
                       float* __restrict__ s_out, float* __restrict__ wsq,
                       bf16_t* __restrict__ wt, bf16_t* __restrict__ zerobuf,
                       bf16_t* __restrict__ xT) {
  __shared__ float tile[32][65];
  __shared__ float s_loc[32];
  int blk = blockIdx.x, t = threadIdx.x;
  if (blk < 1024) {
    wsq_wt_body(blk, t, w, wsq, wt);
  } else if (blk < 2048) {
    style_body(blk - 1024, t, style, fc_w, fc_b, s_out);
  } else if (blk == 2048) {
    if (t < 128) zerobuf[t] = (bf16_t)0.f;      // 256 B
  } else {
    int m = blk - 2049;                          // 0..2047
    int b = m >> 8, rem = m & 255;
    int hq = rem >> 4, fi0 = (rem & 15) * 32;
    // inline style: fi_l = t>>3 owns one fi; 8 lanes x 64-elem partial dots
    int fi_l = t >> 3, part = t & 7;
    const float4* st4 = (const float4*)(style + b * 512);
    const float4* fw4 = (const float4*)(fc_w + (size_t)(fi0 + fi_l) * 512);
    float a = 0.f;
#pragma unroll
    for (int i = 0; i < 16; ++i) {
      float4 sv = st4[part * 16 + i], wv = fw4[part * 16 + i];
      a += sv.x * wv.x + sv.y * wv.y + sv.z * wv.z + sv.w * wv.w;
    }
    a += __shfl_xor(a, 1, 64);
    a += __shfl_xor(a, 2, 64);
    a += __shfl_xor(a, 4, 64);
    if (part == 0) s_loc[fi_l] = a * FCSCALE + fc_b[fi0 + fi_l];
    __syncthreads();
#pragma unroll
    for (int h4 = 0; h4 < 4; ++h4) {
      modx_body_loc(fi0, hq * 4 + h4, b, t, x, s_loc, xT, tile);
      __syncthreads();                           // tile reuse guard
    }
  }
}

// ---- main conv (R11 core) ----
// Shared layout (bf16 elems): [0,24576)  = x bufs: 2 x [6 r][4 g][64 c][8]
//   [24576,32768) = w bufs: 2 x [4 g][128 fo][8];  [32768,32776) = zero slot
//   [32776,33800) = s row (512 f32);  [33800,34056) = dcoef (128 f32)
// Block = 128 fo x 256 px (4 rows), 4 waves. gc loop (16 chunks of 32 fi),
// 9 tap-phases unrolled. Phase P: {VMCNT(N_P); s_barrier; sched_barrier;
//   stage_w(it+1); [stage_x part if P in 1..3]; ds_read frags; 32 MFMA}.
// Prologue additionally: s row -> LDS, inline demod (wsq x s^2 -> rsqrt ->
// dcoef LDS), overlapped with staging loads (raw barrier, no vmcnt drain).
__global__ __launch_bounds__(256, 2) void k_conv(const bf16_t* __restrict__ wt,
                                                 const bf16_t* __restrict__ xT,
                                                 const float* __restrict__ s,
                                                 const float* __restrict__ wsq,
                                                 const bf16_t* __restrict__ zerobuf,
                                                 float* __restrict__ out) {
  __shared__ __align__(16) bf16_t sh[34056];     // 68112 B

  int b   = blockIdx.x;                 // 0..7  (linear%8=b -> XCD-pinned batch)
  int foB = blockIdx.y;                 // 0..3
  int hq  = blockIdx.z;                 // 0..15 -> rows h0..h0+3
  int t = threadIdx.x;
  int wv = t >> 6, lane = t & 63, quad = lane >> 4, l16 = lane & 15;
  int h0 = hq * 4;
  int fo_l = t & 127, chunk_hi = t >> 7;

  const bf16_t* xTb = xT + (size_t)b * 64 * 64 * 64 * 8;   // [h][g][w][8]
  const bf16_t* zslotp = &sh[32768];
  float* s_lds = (float*)&sh[32776];
  float* d_lds = (float*)&sh[33800];
  int XRB = ((wv * 4 + quad) * 64 + l16) * 8;    // per-lane x-frag base (elems)

  floatx4 acc[8][4];
#pragma unroll
  for (int i = 0; i < 8; ++i)
#pragma unroll
    for (int j = 0; j < 4; ++j) acc[i][j] = (floatx4){0.f, 0.f, 0.f, 0.f};

  // ---- prologue: zero slot, stage x(gc=0)->buf0, w(it=0)->buf0, s->LDS,
  //      inline demod (overlapped with staging)
  if (t < 8) sh[32768 + t] = (bf16_t)0.f;
#pragma unroll
  for (int k = 0; k < 3; ++k)
#pragma unroll
    for (int u = 0; u < 2; ++u) {
      int sp = k * 8 + wv * 2 + u;               // 0..23
      int r = sp >> 2, g = sp & 3;
      int rg = h0 + r - 1;
      const bf16_t* src = ((unsigned)rg < 64u)
          ? xTb + (((size_t)rg * 64 + g) * 64 + lane) * 8
          : zerobuf;
      gload_lds16(src, &sh[((r * 4 + g) * 64) * 8]);
    }
#pragma unroll
  for (int itw = 0; itw < 2; ++itw) {
    int cw = itw * 2 + chunk_hi;
    gload_lds16(wt + (((size_t)cw) * 512 + foB * 128 + fo_l) * 8,
                &sh[24576 + (itw * 256 + wv * 64) * 8]);
  }
  if (t < 128)
    ((float4*)s_lds)[t] = ((const float4*)(s + b * 512))[t];
  asm volatile("s_waitcnt lgkmcnt(0)" ::: "memory");  // s_lds + zslot written
  __builtin_amdgcn_s_barrier();                       // staging stays in flight
  __builtin_amdgcn_sched_barrier(0);
  {
    int fo_h = t >> 1, half = t & 1;             // 2 threads per fo
    const float4* wq = (const float4*)(wsq + (size_t)(foB * 128 + fo_h) * 512) + half * 64;
    const float4* sp4 = ((const float4*)s_lds) + half * 64;
    float a = 0.f;
#pragma unroll 8
    for (int i = 0; i < 64; ++i) {
      float4 q = wq[i], sv = sp4[i];
      a += q.x * sv.x * sv.x + q.y * sv.y * sv.y
         + q.z * sv.z * sv.z + q.w * sv.w * sv.w;
    }
    a += __shfl_xor(a, 1, 64);
    if (half == 0) d_lds[fo_h] = rsqrtf(a + 1e-8f);
  }
  VMCNT(0);
  __syncthreads();                               // drains all (staging + d_lds)

#define PHASE(P, NW, XPART, GCLAST)                                            \
  do {                                                                         \
    VMCNT(NW);                                                                 \
    __builtin_amdgcn_s_barrier();                                              \
    __builtin_amdgcn_sched_barrier(0);                                         \
    if (!(GCLAST) || (P) < 8) { /* stage w(it+1) -> buf ((gc9+P+1)&1) */       \
      const int TAP1 = ((P) + 1) % 9;                                          \
      int g01 = ((P) == 8) ? (gc + 1) * 4 : gc * 4;                            \
      int wb1 = ((gc9 + (P) + 1) & 1) * 4096;                                  \
      _Pragma("unroll")                                                        \
      for (int itw = 0; itw < 2; ++itw) {                                      \
        int cw = itw * 2 + chunk_hi;                                           \
        gload_lds16(wt + ((((size_t)TAP1 * 64) + g01 + cw) * 512               \
                          + foB * 128 + fo_l) * 8,                             \
                    &sh[24576 + wb1 + (itw * 256 + wv * 64) * 8]);             \
      }                                                                        \
    }                                                                          \
    if ((XPART) >= 0 && !(GCLAST)) { /* stage x(gc+1) part -> buf ((gc+1)&1) */\
      int xb1 = ((gc + 1) & 1) * 12288;                                        \
      int g0n = (gc + 1) * 4;                                                  \
      _Pragma("unroll")                                                        \
      for (int u = 0; u < 2; ++u) {                                            \
        int sp = (XPART) * 8 + wv * 2 + u;                                     \
        int r = sp >> 2, g = sp & 3;                                           \
        int rg = h0 + r - 1;                                                   \
        const bf16_t* src = ((unsigned)rg < 64u)                               \
            ? xTb + (((size_t)rg * 64 + g0n + g) * 64 + lane) * 8              \
            : zerobuf;                                                         \
        gload_lds16(src, &sh[xb1 + ((r * 4 + g) * 64) * 8]);                   \
      }                                                                        \
    }                                                                          \
    { /* compute(it = gc9+P), tap constants */                                 \
      const int KH = (P) / 3, KW = (P) % 3;                                    \
      int xb = (gc & 1) * 12288;                                               \
      int wb = ((gc9 + (P)) & 1) * 4096;                                       \
      bf16x8 bfr[4];                                                           \
      _Pragma("unroll")                                                        \
      for (int j = 0; j < 4; ++j) {                                            \
        const bf16_t* ap = &sh[xb + XRB + KH * 2048 + (j * 16 + KW - 1) * 8];  \
        if (KW == 0 && (j) == 0) { if (l16 == 0)  ap = zslotp; }               \
        if (KW == 2 && (j) == 3) { if (l16 == 15) ap = zslotp; }               \
        bfr[j] = *(const bf16x8*)ap;                                           \
      }                                                                        \
      __builtin_amdgcn_s_setprio(1);                                           \
      _Pragma("unroll")                                                        \
      for (int i = 0; i < 8; ++i) {                                            \
        bf16x8 afr = *(const bf16x8*)&sh[24576 + wb                            \
                                         + (quad * 128 + i * 16 + l16) * 8];   \
        _Pragma("unroll")                                                      \
        for (int j = 0; j < 4; ++j)                                            \
          acc[i][j] = __builtin_amdgcn_mfma_f32_16x16x32_bf16(                 \
              afr, bfr[j], acc[i][j], 0, 0, 0);                                \
      }                                                                        \
      __builtin_amdgcn_s_setprio(0);                                           \
    }                                                                          \
  } while (0)

  for (int gc = 0; gc < 15; ++gc) {
    int gc9 = gc * 9;
    PHASE(0, 0, -1, false);
    PHASE(1, 0,  0, false);
    PHASE(2, 2,  1, false);
    PHASE(3, 2,  2, false);
    PHASE(4, 2, -1, false);
    PHASE(5, 0, -1, false);
    PHASE(6, 0, -1, false);
    PHASE(7, 0, -1, false);
    PHASE(8, 0, -1, false);
  }
  {
    int gc = 15, gc9 = 135;
    PHASE(0, 0, -1, true);
    PHASE(1, 0, -1, true);
    PHASE(2, 0, -1, true);
    PHASE(3, 0, -1, true);
    PHASE(4, 0, -1, true);
    PHASE(5, 0, -1, true);
    PHASE(6, 0, -1, true);
    PHASE(7, 0, -1, true);
    PHASE(8, 0, -1, true);
  }
#undef PHASE

  // epilogue: C/D col=lane&15 (n=px), row=quad*4+reg (m=fo); demod from LDS
  int h = h0 + wv;
#pragma unroll
  for (int i = 0; i < 8; ++i) {
#pragma unroll
    for (int rr = 0; rr < 4; ++rr) {
      int fo_loc = i * 16 + quad * 4 + rr;
      float dm = d_lds[fo_loc];
      float* op = out + ((size_t)((b * 512 + foB * 128 + fo_loc) * 64 + h)) * 64;
#pragma unroll
      for (int j = 0; j < 4; ++j)
        op[j * 16 + l16] = acc[i][j][rr] * dm;
    }
  }
}

extern "C" void kernel_launch(void* const* d_in, const int* in_sizes, int n_in,
                              void* d_out, int out_size, void* d_ws, size_t ws_size,
                              hipStream_t stream) {
  const float* x     = (const float*)d_in[0];
  const float* style = (const float*)d_in[1];
  const float* w     = (const float*)d_in[2];
  const float* fc_w  = (const float*)d_in[3];
  const float* fc_b  = (const float*)d_in[4];
  float* out = (float*)d_out;
  char* ws = (char*)d_ws;

  float*  s       = (float*)(ws);                  // 16 KB
  float*  wsq     = (float*)(ws + 32768);          // 1 MB
  bf16_t* zerobuf = (bf16_t*)(ws + 1081344);       // 256 B of zeros
  bf16_t* wt      = (bf16_t*)(ws + 1081600);       // 4.5 MB  [tap][g][fo][8]
  bf16_t* xT      = (bf16_t*)(ws + 5800192);       // 32 MB   [b][h][g][w][8]

  k_prep<<<4097, 256, 0, stream>>>(style, fc_w, fc_b, w, x, s, wsq, wt, zerobuf, xT);
  // grid.x = b -> linear block id % 8 == b -> XCD-pinned batch slice
  k_conv<<<dim3(8, 4, 16), 256, 0, stream>>>(wt, xT, s, wsq, zerobuf, out);
}